// Round 11
// baseline (343.827 us; speedup 1.0000x reference)
//
#include <hip/hip_runtime.h>

#define HH 256
#define WW 256
#define CC 16
#define BB 8
#define HID 128
#define HW (HH*WW)
#define CHW (CC*HH*WW)

typedef float  f32x16 __attribute__((ext_vector_type(16)));
typedef short  bf16x8 __attribute__((ext_vector_type(8)));

__device__ __forceinline__ float ldz(const float* __restrict__ p, int h, int w) {
    return (h >= 0 && h < HH && w >= 0 && w < WW) ? p[h * WW + w] : 0.0f;
}

__device__ __forceinline__ unsigned bf16rne(float v) {
    unsigned u = __float_as_uint(v);
    return ((u + 0x7FFFu + ((u >> 16) & 1u)) >> 16) & 0xFFFFu;
}

// Prep: pack fc0 (bias in K-col 48, zero-pad to K=64) and fc1 (M padded to 32)
// into MFMA A-fragment-linear images: slot = frag_id*64 + lane, 16B per slot.
__global__ void prep_frags(const float* __restrict__ fc0w, const float* __restrict__ fc0b,
                           const float* __restrict__ fc1w,
                           uint4* __restrict__ img0, uint4* __restrict__ img1) {
    int t0 = blockIdx.x * 256 + threadIdx.x;
    if (t0 < 2048) {                       // fc0: 32 frags * 64 lanes
        int lane = t0 & 63;
        int fid  = t0 >> 6;                // ((m*4+t)*2+hl)
        int hl = fid & 1, kt = (fid >> 1) & 3, m = fid >> 3;
        int row = 32 * m + (lane & 31);
        int kbase = 16 * kt + 8 * (lane >> 5);
        unsigned d[4];
        #pragma unroll
        for (int dd = 0; dd < 4; ++dd) {
            unsigned half16[2];
            #pragma unroll
            for (int e = 0; e < 2; ++e) {
                int kcol = kbase + 2 * dd + e;
                float v = (kcol < 48) ? fc0w[row * 48 + kcol]
                                      : (kcol == 48 ? fc0b[row] : 0.0f);
                unsigned hb = bf16rne(v);
                if (hl) { float r = v - __uint_as_float(hb << 16); hb = bf16rne(r); }
                half16[e] = hb;
            }
            d[dd] = half16[0] | (half16[1] << 16);
        }
        img0[t0] = make_uint4(d[0], d[1], d[2], d[3]);
    } else if (t0 < 3072) {                // fc1: 16 frags * 64 lanes
        int t1 = t0 - 2048;
        int lane = t1 & 63;
        int fid  = t1 >> 6;                // (t*2+hl)
        int hl = fid & 1, kt = fid >> 1;
        int row = lane & 31;               // out-channel; rows 16..31 zero pad
        int kbase = 16 * kt + 8 * (lane >> 5);
        unsigned d[4];
        #pragma unroll
        for (int dd = 0; dd < 4; ++dd) {
            unsigned half16[2];
            #pragma unroll
            for (int e = 0; e < 2; ++e) {
                int kcol = kbase + 2 * dd + e;
                float v = (row < 16) ? fc1w[row * HID + kcol] : 0.0f;
                unsigned hb = bf16rne(v);
                if (hl) { float r = v - __uint_as_float(hb << 16); hb = bf16rne(r); }
                half16[e] = hb;
            }
            d[dd] = half16[0] | (half16[1] << 16);
        }
        img1[t1] = make_uint4(d[0], d[1], d[2], d[3]);
    }
}

// hi/lo bf16 pack of 8 f32 into two 4-dword fragments
__device__ __forceinline__ void pack8(const float* f, unsigned* hw, unsigned* lw) {
    #pragma unroll
    for (int d = 0; d < 4; ++d) {
        float a = f[2 * d], b = f[2 * d + 1];
        unsigned hi;
        asm("v_cvt_pk_bf16_f32 %0, %1, %2" : "=v"(hi) : "v"(a), "v"(b));
        float ha = __uint_as_float(hi << 16);
        float hb = __uint_as_float(hi & 0xFFFF0000u);
        float ra = a - ha, rb = b - hb;
        unsigned lo;
        asm("v_cvt_pk_bf16_f32 %0, %1, %2" : "=v"(lo) : "v"(ra), "v"(rb));
        hw[d] = hi; lw[d] = lo;
    }
}

__device__ __forceinline__ bf16x8 frag_of(uint4 u) { return __builtin_bit_cast(bf16x8, u); }

// Perceive + per-pixel MLP via MFMA 32x32x16 bf16x3. One wave = 32 pixels;
// lane (q,p): q=lane>>5 handles channels 8q..8q+7 of pixel p=lane&31.
// ROUND-8-EXACT except the epilogue: centers are redistributed from fid[]
// via 4 permlane32_swap instead of re-reading x (bisect experiment: isolates
// the fid-swap change from the life-fusion change that NaN'd in rounds 9/10).
__global__ __launch_bounds__(128, 2) void ca_step_mlp(
    const float* __restrict__ x,      // [B,C,H,W]
    const uint4* __restrict__ img0,   // fc0 A-frags
    const uint4* __restrict__ img1,   // fc1 A-frags
    const float* __restrict__ mask,   // [B,H,W] this step
    float* __restrict__ xn,           // [B,C,H,W]
    float* __restrict__ pre)          // [B,H,W]
{
    const int tid  = threadIdx.x;
    const int lane = tid & 63;
    const int p = lane & 31, q = lane >> 5;
    const int w = blockIdx.x * 64 + (tid >> 6) * 32 + p;
    const int h = blockIdx.y;
    const int b = blockIdx.z;
    const float* __restrict__ xb = x + (size_t)b * CHW;

    // ---- perceive: channels q*8 .. q*8+7 of pixel (h,w) ----
    float fid[8], fsx[8], fsy[8];
    float prem = -1.0f;
    #pragma unroll
    for (int cc = 0; cc < 8; ++cc) {
        const float* __restrict__ pc = xb + (q * 8 + cc) * HW;
        float v00 = ldz(pc, h - 1, w - 1), v01 = ldz(pc, h - 1, w), v02 = ldz(pc, h - 1, w + 1);
        float v10 = ldz(pc, h,     w - 1), v11 = pc[h * WW + w],    v12 = ldz(pc, h,     w + 1);
        float v20 = ldz(pc, h + 1, w - 1), v21 = ldz(pc, h + 1, w), v22 = ldz(pc, h + 1, w + 1);
        fid[cc] = v11;
        fsx[cc] = ((v02 - v00) + 2.0f * (v12 - v10) + (v22 - v20)) * 0.125f;
        fsy[cc] = ((v20 - v00) + 2.0f * (v21 - v01) + (v22 - v02)) * 0.125f;
        if (cc == 3) {
            float m = fmaxf(fmaxf(fmaxf(v00, v01), fmaxf(v02, v10)),
                            fmaxf(fmaxf(v11, v12), fmaxf(fmaxf(v20, v21), v22)));
            prem = m;
        }
    }
    if (q == 0)   // zero-padded max == -inf-padded max for the >0.1 test
        pre[((size_t)b * HH + h) * WW + w] = (prem > 0.1f) ? 1.0f : 0.0f;

    // ---- pack fc0 B fragments (K-steps: t0=id, t1=sx, t2=sy) ----
    unsigned bh[3][4], bl[3][4];
    pack8(fid, bh[0], bl[0]);
    pack8(fsx, bh[1], bl[1]);
    pack8(fsy, bh[2], bl[2]);
    // t3: bias column -> feature 48 = 1.0 (q==0, j==0), rest 0
    unsigned b3[4] = { (q == 0) ? 0x00003F80u : 0u, 0u, 0u, 0u };
    bf16x8 B3 = __builtin_bit_cast(bf16x8, make_uint4(b3[0], b3[1], b3[2], b3[3]));

    f32x16 dC;
    #pragma unroll
    for (int i = 0; i < 16; ++i) dC[i] = 0.0f;

    #pragma unroll
    for (int m = 0; m < 4; ++m) {
        // fc0 M-tile m: h rows 32m..32m+31
        f32x16 C;
        #pragma unroll
        for (int i = 0; i < 16; ++i) C[i] = 0.0f;
        #pragma unroll
        for (int t = 0; t < 3; ++t) {
            bf16x8 Ah = frag_of(img0[((m * 4 + t) * 2 + 0) * 64 + lane]);
            bf16x8 Al = frag_of(img0[((m * 4 + t) * 2 + 1) * 64 + lane]);
            bf16x8 Bh = __builtin_bit_cast(bf16x8, make_uint4(bh[t][0], bh[t][1], bh[t][2], bh[t][3]));
            bf16x8 Bl = __builtin_bit_cast(bf16x8, make_uint4(bl[t][0], bl[t][1], bl[t][2], bl[t][3]));
            C = __builtin_amdgcn_mfma_f32_32x32x16_bf16(Ah, Bh, C, 0, 0, 0);
            C = __builtin_amdgcn_mfma_f32_32x32x16_bf16(Ah, Bl, C, 0, 0, 0);
            C = __builtin_amdgcn_mfma_f32_32x32x16_bf16(Al, Bh, C, 0, 0, 0);
        }
        {   // bias K-step (B lo-part is zero -> 2 products)
            bf16x8 Ah = frag_of(img0[((m * 4 + 3) * 2 + 0) * 64 + lane]);
            bf16x8 Al = frag_of(img0[((m * 4 + 3) * 2 + 1) * 64 + lane]);
            C = __builtin_amdgcn_mfma_f32_32x32x16_bf16(Ah, B3, C, 0, 0, 0);
            C = __builtin_amdgcn_mfma_f32_32x32x16_bf16(Al, B3, C, 0, 0, 0);
        }
        // relu
        #pragma unroll
        for (int i = 0; i < 16; ++i) C[i] = fmaxf(C[i], 0.0f);

        // C-layout -> fc1 B-layout via permlane32_swap, then hi/lo pack
        #pragma unroll
        for (int half = 0; half < 2; ++half) {
            float ar[4], br[4];
            #pragma unroll
            for (int r = 0; r < 4; ++r) { ar[r] = C[8 * half + r]; br[r] = C[8 * half + 4 + r]; }
            #pragma unroll
            for (int r = 0; r < 4; ++r)
                asm("v_permlane32_swap_b32 %0, %1" : "+v"(ar[r]), "+v"(br[r]));
            float v8[8] = { ar[0], ar[1], ar[2], ar[3], br[0], br[1], br[2], br[3] };
            unsigned hbw[4], lbw[4];
            pack8(v8, hbw, lbw);
            bf16x8 Bh = __builtin_bit_cast(bf16x8, make_uint4(hbw[0], hbw[1], hbw[2], hbw[3]));
            bf16x8 Bl = __builtin_bit_cast(bf16x8, make_uint4(lbw[0], lbw[1], lbw[2], lbw[3]));
            const int t = 2 * m + half;
            bf16x8 A1h = frag_of(img1[(t * 2 + 0) * 64 + lane]);
            bf16x8 A1l = frag_of(img1[(t * 2 + 1) * 64 + lane]);
            dC = __builtin_amdgcn_mfma_f32_32x32x16_bf16(A1h, Bh, dC, 0, 0, 0);
            dC = __builtin_amdgcn_mfma_f32_32x32x16_bf16(A1h, Bl, dC, 0, 0, 0);
            dC = __builtin_amdgcn_mfma_f32_32x32x16_bf16(A1l, Bh, dC, 0, 0, 0);
        }
    }

    // redistribute centers: after swaps fid[r] = center of channel 4q+(r&3)+8(r>>2)
    #pragma unroll
    for (int j = 0; j < 4; ++j)
        asm("v_permlane32_swap_b32 %0, %1" : "+v"(fid[j]), "+v"(fid[j + 4]));

    const size_t pix = (size_t)h * WW + w;
    const float mk = mask[(size_t)b * HW + pix];
    float* __restrict__ xnb = xn + (size_t)b * CHW;
    #pragma unroll
    for (int r = 0; r < 8; ++r) {
        int c = 4 * q + (r & 3) + 8 * (r >> 2);
        xnb[c * HW + pix] = fid[r] + dC[r] * mk;
    }
}

// Per-step life kernel: post = maxpool3(xn[:,3]) > 0.1; out = xn * (pre & post)
__global__ __launch_bounds__(256) void ca_step_life(
    const float* __restrict__ xn,
    const float* __restrict__ pre,
    float* __restrict__ xout)
{
    const int tid = threadIdx.x;
    const int w = blockIdx.x * 64 + (tid & 63);
    const int h = blockIdx.y * 4 + (tid >> 6);
    const int b = blockIdx.z;
    const float* __restrict__ alpha = xn + ((size_t)b * CC + 3) * HW;

    float m = fmaxf(fmaxf(fmaxf(ldz(alpha, h - 1, w - 1), ldz(alpha, h - 1, w)),
                          fmaxf(ldz(alpha, h - 1, w + 1), ldz(alpha, h, w - 1))),
                    fmaxf(fmaxf(alpha[h * WW + w], ldz(alpha, h, w + 1)),
                          fmaxf(fmaxf(ldz(alpha, h + 1, w - 1), ldz(alpha, h + 1, w)),
                                ldz(alpha, h + 1, w + 1))));
    const float prev = pre[((size_t)b * HH + h) * WW + w];
    const float life = (m > 0.1f && prev > 0.5f) ? 1.0f : 0.0f;

    const float* __restrict__ xnb = xn + (size_t)b * CHW;
    float* __restrict__ xob = xout + (size_t)b * CHW;
    const size_t pix = (size_t)h * WW + w;
    #pragma unroll
    for (int c = 0; c < 16; ++c) xob[c * HW + pix] = xnb[c * HW + pix] * life;
}

extern "C" void kernel_launch(void* const* d_in, const int* in_sizes, int n_in,
                              void* d_out, int out_size, void* d_ws, size_t ws_size,
                              hipStream_t stream) {
    const float* x      = (const float*)d_in[0];  // [8,16,256,256]
    const float* fc0w   = (const float*)d_in[1];  // [128,48]
    const float* fc0b   = (const float*)d_in[2];  // [128]
    const float* fc1w   = (const float*)d_in[3];  // [16,128]
    const float* stoch  = (const float*)d_in[4];  // [4,8,1,256,256]
    float* out = (float*)d_out;

    float* ws    = (float*)d_ws;
    float* xn    = ws;                          // 8388608 floats
    float* xtmp  = ws + (size_t)BB * CHW;       // 8388608 floats
    float* pre   = xtmp + (size_t)BB * CHW;     // 524288 floats
    uint4* img0  = (uint4*)(pre + (size_t)BB * HW);   // 2048 uint4 (32 KB)
    uint4* img1  = img0 + 2048;                       // 1024 uint4 (16 KB)

    prep_frags<<<12, 256, 0, stream>>>(fc0w, fc0b, fc1w, img0, img1);

    dim3 gridM(WW / 64, HH, BB);     // 128 threads = 2 waves, 32 px each
    dim3 gridL(WW / 64, HH / 4, BB);

    for (int s = 0; s < 4; ++s) {
        const float* xin = (s == 0) ? x : xtmp;
        const float* msk = stoch + (size_t)s * BB * HW;
        ca_step_mlp<<<gridM, dim3(128), 0, stream>>>(xin, img0, img1, msk, xn, pre);
        float* xo = (s == 3) ? out : xtmp;
        ca_step_life<<<gridL, dim3(256), 0, stream>>>(xn, pre, xo);
    }
}

// Round 12
// 337.943 us; speedup vs baseline: 1.0174x; 1.0174x over previous
//
#include <hip/hip_runtime.h>

#define HH 256
#define WW 256
#define CC 16
#define BB 8
#define HID 128
#define HW (HH*WW)
#define CHW (CC*HH*WW)

typedef float  f32x16 __attribute__((ext_vector_type(16)));
typedef short  bf16x8 __attribute__((ext_vector_type(8)));

__device__ __forceinline__ float ldz(const float* __restrict__ p, int h, int w) {
    return (h >= 0 && h < HH && w >= 0 && w < WW) ? p[h * WW + w] : 0.0f;
}

__device__ __forceinline__ unsigned bf16rne(float v) {
    unsigned u = __float_as_uint(v);
    return ((u + 0x7FFFu + ((u >> 16) & 1u)) >> 16) & 0xFFFFu;
}

// Prep: pack fc0 (bias in K-col 48, zero-pad to K=64) and fc1 (M padded to 32)
// into MFMA A-fragment-linear images: slot = frag_id*64 + lane, 16B per slot.
__global__ void prep_frags(const float* __restrict__ fc0w, const float* __restrict__ fc0b,
                           const float* __restrict__ fc1w,
                           uint4* __restrict__ img0, uint4* __restrict__ img1) {
    int t0 = blockIdx.x * 256 + threadIdx.x;
    if (t0 < 2048) {                       // fc0: 32 frags * 64 lanes
        int lane = t0 & 63;
        int fid  = t0 >> 6;                // ((m*4+t)*2+hl)
        int hl = fid & 1, kt = (fid >> 1) & 3, m = fid >> 3;
        int row = 32 * m + (lane & 31);
        int kbase = 16 * kt + 8 * (lane >> 5);
        unsigned d[4];
        #pragma unroll
        for (int dd = 0; dd < 4; ++dd) {
            unsigned half16[2];
            #pragma unroll
            for (int e = 0; e < 2; ++e) {
                int kcol = kbase + 2 * dd + e;
                float v = (kcol < 48) ? fc0w[row * 48 + kcol]
                                      : (kcol == 48 ? fc0b[row] : 0.0f);
                unsigned hb = bf16rne(v);
                if (hl) { float r = v - __uint_as_float(hb << 16); hb = bf16rne(r); }
                half16[e] = hb;
            }
            d[dd] = half16[0] | (half16[1] << 16);
        }
        img0[t0] = make_uint4(d[0], d[1], d[2], d[3]);
    } else if (t0 < 3072) {                // fc1: 16 frags * 64 lanes
        int t1 = t0 - 2048;
        int lane = t1 & 63;
        int fid  = t1 >> 6;                // (t*2+hl)
        int hl = fid & 1, kt = fid >> 1;
        int row = lane & 31;               // out-channel; rows 16..31 zero pad
        int kbase = 16 * kt + 8 * (lane >> 5);
        unsigned d[4];
        #pragma unroll
        for (int dd = 0; dd < 4; ++dd) {
            unsigned half16[2];
            #pragma unroll
            for (int e = 0; e < 2; ++e) {
                int kcol = kbase + 2 * dd + e;
                float v = (row < 16) ? fc1w[row * HID + kcol] : 0.0f;
                unsigned hb = bf16rne(v);
                if (hl) { float r = v - __uint_as_float(hb << 16); hb = bf16rne(r); }
                half16[e] = hb;
            }
            d[dd] = half16[0] | (half16[1] << 16);
        }
        img1[t1] = make_uint4(d[0], d[1], d[2], d[3]);
    }
}

// hi/lo bf16 pack of 8 f32 into two 4-dword fragments
__device__ __forceinline__ void pack8(const float* f, unsigned* hw, unsigned* lw) {
    #pragma unroll
    for (int d = 0; d < 4; ++d) {
        float a = f[2 * d], b = f[2 * d + 1];
        unsigned hi;
        asm("v_cvt_pk_bf16_f32 %0, %1, %2" : "=v"(hi) : "v"(a), "v"(b));
        float ha = __uint_as_float(hi << 16);
        float hb = __uint_as_float(hi & 0xFFFF0000u);
        float ra = a - ha, rb = b - hb;
        unsigned lo;
        asm("v_cvt_pk_bf16_f32 %0, %1, %2" : "=v"(lo) : "v"(ra), "v"(rb));
        hw[d] = hi; lw[d] = lo;
    }
}

__device__ __forceinline__ bf16x8 frag_of(uint4 u) { return __builtin_bit_cast(bf16x8, u); }

// Perceive + per-pixel MLP via MFMA 32x32x16 bf16x3. Per-wave code identical
// to round 11 (passing); launch geometry changed: 512-thread blocks = 8 waves
// covering 64 px x 4 rows. wave wv = tid>>6: row = wv>>1, x-half = wv&1.
// Rationale: 1-row blocks re-fetched vertical halo rows from HBM/L2 (FETCH
// 58.8 vs 33.5 MB ideal) and 2-wave workgroups left occupancy at 36%; fat
// blocks share rows via L1 and pack CUs fuller.
__global__ __launch_bounds__(512) void ca_step_mlp(
    const float* __restrict__ x,      // [B,C,H,W]
    const uint4* __restrict__ img0,   // fc0 A-frags
    const uint4* __restrict__ img1,   // fc1 A-frags
    const float* __restrict__ mask,   // [B,H,W] this step
    float* __restrict__ xn,           // [B,C,H,W]
    float* __restrict__ pre)          // [B,H,W]
{
    const int tid  = threadIdx.x;
    const int lane = tid & 63;
    const int p = lane & 31, q = lane >> 5;
    const int wv = tid >> 6;                       // 0..7
    const int w = blockIdx.x * 64 + (wv & 1) * 32 + p;
    const int h = blockIdx.y * 4 + (wv >> 1);
    const int b = blockIdx.z;
    const float* __restrict__ xb = x + (size_t)b * CHW;

    // ---- perceive: channels q*8 .. q*8+7 of pixel (h,w) ----
    float fid[8], fsx[8], fsy[8];
    float prem = -1.0f;
    #pragma unroll
    for (int cc = 0; cc < 8; ++cc) {
        const float* __restrict__ pc = xb + (q * 8 + cc) * HW;
        float v00 = ldz(pc, h - 1, w - 1), v01 = ldz(pc, h - 1, w), v02 = ldz(pc, h - 1, w + 1);
        float v10 = ldz(pc, h,     w - 1), v11 = pc[h * WW + w],    v12 = ldz(pc, h,     w + 1);
        float v20 = ldz(pc, h + 1, w - 1), v21 = ldz(pc, h + 1, w), v22 = ldz(pc, h + 1, w + 1);
        fid[cc] = v11;
        fsx[cc] = ((v02 - v00) + 2.0f * (v12 - v10) + (v22 - v20)) * 0.125f;
        fsy[cc] = ((v20 - v00) + 2.0f * (v21 - v01) + (v22 - v02)) * 0.125f;
        if (cc == 3) {
            float m = fmaxf(fmaxf(fmaxf(v00, v01), fmaxf(v02, v10)),
                            fmaxf(fmaxf(v11, v12), fmaxf(fmaxf(v20, v21), v22)));
            prem = m;
        }
    }
    if (q == 0)   // zero-padded max == -inf-padded max for the >0.1 test
        pre[((size_t)b * HH + h) * WW + w] = (prem > 0.1f) ? 1.0f : 0.0f;

    // ---- pack fc0 B fragments (K-steps: t0=id, t1=sx, t2=sy) ----
    unsigned bh[3][4], bl[3][4];
    pack8(fid, bh[0], bl[0]);
    pack8(fsx, bh[1], bl[1]);
    pack8(fsy, bh[2], bl[2]);
    // t3: bias column -> feature 48 = 1.0 (q==0, j==0), rest 0
    unsigned b3[4] = { (q == 0) ? 0x00003F80u : 0u, 0u, 0u, 0u };
    bf16x8 B3 = __builtin_bit_cast(bf16x8, make_uint4(b3[0], b3[1], b3[2], b3[3]));

    f32x16 dC;
    #pragma unroll
    for (int i = 0; i < 16; ++i) dC[i] = 0.0f;

    #pragma unroll
    for (int m = 0; m < 4; ++m) {
        // fc0 M-tile m: h rows 32m..32m+31
        f32x16 C;
        #pragma unroll
        for (int i = 0; i < 16; ++i) C[i] = 0.0f;
        #pragma unroll
        for (int t = 0; t < 3; ++t) {
            bf16x8 Ah = frag_of(img0[((m * 4 + t) * 2 + 0) * 64 + lane]);
            bf16x8 Al = frag_of(img0[((m * 4 + t) * 2 + 1) * 64 + lane]);
            bf16x8 Bh = __builtin_bit_cast(bf16x8, make_uint4(bh[t][0], bh[t][1], bh[t][2], bh[t][3]));
            bf16x8 Bl = __builtin_bit_cast(bf16x8, make_uint4(bl[t][0], bl[t][1], bl[t][2], bl[t][3]));
            C = __builtin_amdgcn_mfma_f32_32x32x16_bf16(Ah, Bh, C, 0, 0, 0);
            C = __builtin_amdgcn_mfma_f32_32x32x16_bf16(Ah, Bl, C, 0, 0, 0);
            C = __builtin_amdgcn_mfma_f32_32x32x16_bf16(Al, Bh, C, 0, 0, 0);
        }
        {   // bias K-step (B lo-part is zero -> 2 products)
            bf16x8 Ah = frag_of(img0[((m * 4 + 3) * 2 + 0) * 64 + lane]);
            bf16x8 Al = frag_of(img0[((m * 4 + 3) * 2 + 1) * 64 + lane]);
            C = __builtin_amdgcn_mfma_f32_32x32x16_bf16(Ah, B3, C, 0, 0, 0);
            C = __builtin_amdgcn_mfma_f32_32x32x16_bf16(Al, B3, C, 0, 0, 0);
        }
        // relu
        #pragma unroll
        for (int i = 0; i < 16; ++i) C[i] = fmaxf(C[i], 0.0f);

        // C-layout -> fc1 B-layout via permlane32_swap, then hi/lo pack
        #pragma unroll
        for (int half = 0; half < 2; ++half) {
            float ar[4], br[4];
            #pragma unroll
            for (int r = 0; r < 4; ++r) { ar[r] = C[8 * half + r]; br[r] = C[8 * half + 4 + r]; }
            #pragma unroll
            for (int r = 0; r < 4; ++r)
                asm("v_permlane32_swap_b32 %0, %1" : "+v"(ar[r]), "+v"(br[r]));
            float v8[8] = { ar[0], ar[1], ar[2], ar[3], br[0], br[1], br[2], br[3] };
            unsigned hbw[4], lbw[4];
            pack8(v8, hbw, lbw);
            bf16x8 Bh = __builtin_bit_cast(bf16x8, make_uint4(hbw[0], hbw[1], hbw[2], hbw[3]));
            bf16x8 Bl = __builtin_bit_cast(bf16x8, make_uint4(lbw[0], lbw[1], lbw[2], lbw[3]));
            const int t = 2 * m + half;
            bf16x8 A1h = frag_of(img1[(t * 2 + 0) * 64 + lane]);
            bf16x8 A1l = frag_of(img1[(t * 2 + 1) * 64 + lane]);
            dC = __builtin_amdgcn_mfma_f32_32x32x16_bf16(A1h, Bh, dC, 0, 0, 0);
            dC = __builtin_amdgcn_mfma_f32_32x32x16_bf16(A1h, Bl, dC, 0, 0, 0);
            dC = __builtin_amdgcn_mfma_f32_32x32x16_bf16(A1l, Bh, dC, 0, 0, 0);
        }
    }

    // redistribute centers: after swaps fid[r] = center of channel 4q+(r&3)+8(r>>2)
    #pragma unroll
    for (int j = 0; j < 4; ++j)
        asm("v_permlane32_swap_b32 %0, %1" : "+v"(fid[j]), "+v"(fid[j + 4]));

    const size_t pix = (size_t)h * WW + w;
    const float mk = mask[(size_t)b * HW + pix];
    float* __restrict__ xnb = xn + (size_t)b * CHW;
    #pragma unroll
    for (int r = 0; r < 8; ++r) {
        int c = 4 * q + (r & 3) + 8 * (r >> 2);
        xnb[c * HW + pix] = fid[r] + dC[r] * mk;
    }
}

// Per-step life kernel: post = maxpool3(xn[:,3]) > 0.1; out = xn * (pre & post)
__global__ __launch_bounds__(256) void ca_step_life(
    const float* __restrict__ xn,
    const float* __restrict__ pre,
    float* __restrict__ xout)
{
    const int tid = threadIdx.x;
    const int w = blockIdx.x * 64 + (tid & 63);
    const int h = blockIdx.y * 4 + (tid >> 6);
    const int b = blockIdx.z;
    const float* __restrict__ alpha = xn + ((size_t)b * CC + 3) * HW;

    float m = fmaxf(fmaxf(fmaxf(ldz(alpha, h - 1, w - 1), ldz(alpha, h - 1, w)),
                          fmaxf(ldz(alpha, h - 1, w + 1), ldz(alpha, h, w - 1))),
                    fmaxf(fmaxf(alpha[h * WW + w], ldz(alpha, h, w + 1)),
                          fmaxf(fmaxf(ldz(alpha, h + 1, w - 1), ldz(alpha, h + 1, w)),
                                ldz(alpha, h + 1, w + 1))));
    const float prev = pre[((size_t)b * HH + h) * WW + w];
    const float life = (m > 0.1f && prev > 0.5f) ? 1.0f : 0.0f;

    const float* __restrict__ xnb = xn + (size_t)b * CHW;
    float* __restrict__ xob = xout + (size_t)b * CHW;
    const size_t pix = (size_t)h * WW + w;
    #pragma unroll
    for (int c = 0; c < 16; ++c) xob[c * HW + pix] = xnb[c * HW + pix] * life;
}

extern "C" void kernel_launch(void* const* d_in, const int* in_sizes, int n_in,
                              void* d_out, int out_size, void* d_ws, size_t ws_size,
                              hipStream_t stream) {
    const float* x      = (const float*)d_in[0];  // [8,16,256,256]
    const float* fc0w   = (const float*)d_in[1];  // [128,48]
    const float* fc0b   = (const float*)d_in[2];  // [128]
    const float* fc1w   = (const float*)d_in[3];  // [16,128]
    const float* stoch  = (const float*)d_in[4];  // [4,8,1,256,256]
    float* out = (float*)d_out;

    float* ws    = (float*)d_ws;
    float* xn    = ws;                          // 8388608 floats
    float* xtmp  = ws + (size_t)BB * CHW;       // 8388608 floats
    float* pre   = xtmp + (size_t)BB * CHW;     // 524288 floats
    uint4* img0  = (uint4*)(pre + (size_t)BB * HW);   // 2048 uint4 (32 KB)
    uint4* img1  = img0 + 2048;                       // 1024 uint4 (16 KB)

    prep_frags<<<12, 256, 0, stream>>>(fc0w, fc0b, fc1w, img0, img1);

    dim3 gridM(WW / 64, HH / 4, BB);   // 512 threads = 8 waves = 64 px x 4 rows
    dim3 gridL(WW / 64, HH / 4, BB);

    for (int s = 0; s < 4; ++s) {
        const float* xin = (s == 0) ? x : xtmp;
        const float* msk = stoch + (size_t)s * BB * HW;
        ca_step_mlp<<<gridM, dim3(512), 0, stream>>>(xin, img0, img1, msk, xn, pre);
        float* xo = (s == 3) ? out : xtmp;
        ca_step_life<<<gridL, dim3(256), 0, stream>>>(xn, pre, xo);
    }
}

// Round 15
// 333.838 us; speedup vs baseline: 1.0299x; 1.0123x over previous
//
#include <hip/hip_runtime.h>

#define HH 256
#define WW 256
#define CC 16
#define BB 8
#define HID 128
#define HW (HH*WW)
#define CHW (CC*HH*WW)

typedef float  f32x16 __attribute__((ext_vector_type(16)));
typedef float  f32x4  __attribute__((ext_vector_type(4)));
typedef short  bf16x8 __attribute__((ext_vector_type(8)));

__device__ __forceinline__ float ldz(const float* __restrict__ p, int h, int w) {
    return (h >= 0 && h < HH && w >= 0 && w < WW) ? p[h * WW + w] : 0.0f;
}

__device__ __forceinline__ unsigned bf16rne(float v) {
    unsigned u = __float_as_uint(v);
    return ((u + 0x7FFFu + ((u >> 16) & 1u)) >> 16) & 0xFFFFu;
}

// Prep: pack fc0 (bias in K-col 48, zero-pad to K=64) and fc1 (M padded to 32)
// into MFMA A-fragment-linear images: slot = frag_id*64 + lane, 16B per slot.
__global__ void prep_frags(const float* __restrict__ fc0w, const float* __restrict__ fc0b,
                           const float* __restrict__ fc1w,
                           uint4* __restrict__ img0, uint4* __restrict__ img1) {
    int t0 = blockIdx.x * 256 + threadIdx.x;
    if (t0 < 2048) {                       // fc0: 32 frags * 64 lanes
        int lane = t0 & 63;
        int fid  = t0 >> 6;                // ((m*4+t)*2+hl)
        int hl = fid & 1, kt = (fid >> 1) & 3, m = fid >> 3;
        int row = 32 * m + (lane & 31);
        int kbase = 16 * kt + 8 * (lane >> 5);
        unsigned d[4];
        #pragma unroll
        for (int dd = 0; dd < 4; ++dd) {
            unsigned half16[2];
            #pragma unroll
            for (int e = 0; e < 2; ++e) {
                int kcol = kbase + 2 * dd + e;
                float v = (kcol < 48) ? fc0w[row * 48 + kcol]
                                      : (kcol == 48 ? fc0b[row] : 0.0f);
                unsigned hb = bf16rne(v);
                if (hl) { float r = v - __uint_as_float(hb << 16); hb = bf16rne(r); }
                half16[e] = hb;
            }
            d[dd] = half16[0] | (half16[1] << 16);
        }
        img0[t0] = make_uint4(d[0], d[1], d[2], d[3]);
    } else if (t0 < 3072) {                // fc1: 16 frags * 64 lanes
        int t1 = t0 - 2048;
        int lane = t1 & 63;
        int fid  = t1 >> 6;                // (t*2+hl)
        int hl = fid & 1, kt = fid >> 1;
        int row = lane & 31;               // out-channel; rows 16..31 zero pad
        int kbase = 16 * kt + 8 * (lane >> 5);
        unsigned d[4];
        #pragma unroll
        for (int dd = 0; dd < 4; ++dd) {
            unsigned half16[2];
            #pragma unroll
            for (int e = 0; e < 2; ++e) {
                int kcol = kbase + 2 * dd + e;
                float v = (row < 16) ? fc1w[row * HID + kcol] : 0.0f;
                unsigned hb = bf16rne(v);
                if (hl) { float r = v - __uint_as_float(hb << 16); hb = bf16rne(r); }
                half16[e] = hb;
            }
            d[dd] = half16[0] | (half16[1] << 16);
        }
        img1[t1] = make_uint4(d[0], d[1], d[2], d[3]);
    }
}

// hi/lo bf16 pack of 8 f32 into two 4-dword fragments
__device__ __forceinline__ void pack8(const float* f, unsigned* hw, unsigned* lw) {
    #pragma unroll
    for (int d = 0; d < 4; ++d) {
        float a = f[2 * d], b = f[2 * d + 1];
        unsigned hi;
        asm("v_cvt_pk_bf16_f32 %0, %1, %2" : "=v"(hi) : "v"(a), "v"(b));
        float ha = __uint_as_float(hi << 16);
        float hb = __uint_as_float(hi & 0xFFFF0000u);
        float ra = a - ha, rb = b - hb;
        unsigned lo;
        asm("v_cvt_pk_bf16_f32 %0, %1, %2" : "=v"(lo) : "v"(ra), "v"(rb));
        hw[d] = hi; lw[d] = lo;
    }
}

__device__ __forceinline__ bf16x8 frag_of(uint4 u) { return __builtin_bit_cast(bf16x8, u); }

// Perceive + per-pixel MLP via MFMA 32x32x16 bf16x3. ROUND-12-EXACT (the
// passing version: scalar ldz stencil, 512-thread blocks = 8 waves over
// 64 px x 4 rows). Round 13's ld4u fast path is under bisect suspicion and
// is removed this round.
__global__ __launch_bounds__(512) void ca_step_mlp(
    const float* __restrict__ x,      // [B,C,H,W]
    const uint4* __restrict__ img0,   // fc0 A-frags
    const uint4* __restrict__ img1,   // fc1 A-frags
    const float* __restrict__ mask,   // [B,H,W] this step
    float* __restrict__ xn,           // [B,C,H,W]
    float* __restrict__ pre)          // [B,H,W]
{
    const int tid  = threadIdx.x;
    const int lane = tid & 63;
    const int p = lane & 31, q = lane >> 5;
    const int wv = tid >> 6;                       // 0..7
    const int w = blockIdx.x * 64 + (wv & 1) * 32 + p;
    const int h = blockIdx.y * 4 + (wv >> 1);
    const int b = blockIdx.z;
    const float* __restrict__ xb = x + (size_t)b * CHW;

    // ---- perceive: channels q*8 .. q*8+7 of pixel (h,w) ----
    float fid[8], fsx[8], fsy[8];
    float prem = -1.0f;
    #pragma unroll
    for (int cc = 0; cc < 8; ++cc) {
        const float* __restrict__ pc = xb + (q * 8 + cc) * HW;
        float v00 = ldz(pc, h - 1, w - 1), v01 = ldz(pc, h - 1, w), v02 = ldz(pc, h - 1, w + 1);
        float v10 = ldz(pc, h,     w - 1), v11 = pc[h * WW + w],    v12 = ldz(pc, h,     w + 1);
        float v20 = ldz(pc, h + 1, w - 1), v21 = ldz(pc, h + 1, w), v22 = ldz(pc, h + 1, w + 1);
        fid[cc] = v11;
        fsx[cc] = ((v02 - v00) + 2.0f * (v12 - v10) + (v22 - v20)) * 0.125f;
        fsy[cc] = ((v20 - v00) + 2.0f * (v21 - v01) + (v22 - v02)) * 0.125f;
        if (cc == 3) {
            float m = fmaxf(fmaxf(fmaxf(v00, v01), fmaxf(v02, v10)),
                            fmaxf(fmaxf(v11, v12), fmaxf(fmaxf(v20, v21), v22)));
            prem = m;
        }
    }
    if (q == 0)   // zero-padded max == -inf-padded max for the >0.1 test
        pre[((size_t)b * HH + h) * WW + w] = (prem > 0.1f) ? 1.0f : 0.0f;

    // ---- pack fc0 B fragments (K-steps: t0=id, t1=sx, t2=sy) ----
    unsigned bh[3][4], bl[3][4];
    pack8(fid, bh[0], bl[0]);
    pack8(fsx, bh[1], bl[1]);
    pack8(fsy, bh[2], bl[2]);
    // t3: bias column -> feature 48 = 1.0 (q==0, j==0), rest 0
    unsigned b3[4] = { (q == 0) ? 0x00003F80u : 0u, 0u, 0u, 0u };
    bf16x8 B3 = __builtin_bit_cast(bf16x8, make_uint4(b3[0], b3[1], b3[2], b3[3]));

    f32x16 dC;
    #pragma unroll
    for (int i = 0; i < 16; ++i) dC[i] = 0.0f;

    #pragma unroll
    for (int m = 0; m < 4; ++m) {
        // fc0 M-tile m: h rows 32m..32m+31
        f32x16 C;
        #pragma unroll
        for (int i = 0; i < 16; ++i) C[i] = 0.0f;
        #pragma unroll
        for (int t = 0; t < 3; ++t) {
            bf16x8 Ah = frag_of(img0[((m * 4 + t) * 2 + 0) * 64 + lane]);
            bf16x8 Al = frag_of(img0[((m * 4 + t) * 2 + 1) * 64 + lane]);
            bf16x8 Bh = __builtin_bit_cast(bf16x8, make_uint4(bh[t][0], bh[t][1], bh[t][2], bh[t][3]));
            bf16x8 Bl = __builtin_bit_cast(bf16x8, make_uint4(bl[t][0], bl[t][1], bl[t][2], bl[t][3]));
            C = __builtin_amdgcn_mfma_f32_32x32x16_bf16(Ah, Bh, C, 0, 0, 0);
            C = __builtin_amdgcn_mfma_f32_32x32x16_bf16(Ah, Bl, C, 0, 0, 0);
            C = __builtin_amdgcn_mfma_f32_32x32x16_bf16(Al, Bh, C, 0, 0, 0);
        }
        {   // bias K-step (B lo-part is zero -> 2 products)
            bf16x8 Ah = frag_of(img0[((m * 4 + 3) * 2 + 0) * 64 + lane]);
            bf16x8 Al = frag_of(img0[((m * 4 + 3) * 2 + 1) * 64 + lane]);
            C = __builtin_amdgcn_mfma_f32_32x32x16_bf16(Ah, B3, C, 0, 0, 0);
            C = __builtin_amdgcn_mfma_f32_32x32x16_bf16(Al, B3, C, 0, 0, 0);
        }
        // relu
        #pragma unroll
        for (int i = 0; i < 16; ++i) C[i] = fmaxf(C[i], 0.0f);

        // C-layout -> fc1 B-layout via permlane32_swap, then hi/lo pack
        #pragma unroll
        for (int half = 0; half < 2; ++half) {
            float ar[4], br[4];
            #pragma unroll
            for (int r = 0; r < 4; ++r) { ar[r] = C[8 * half + r]; br[r] = C[8 * half + 4 + r]; }
            #pragma unroll
            for (int r = 0; r < 4; ++r)
                asm("v_permlane32_swap_b32 %0, %1" : "+v"(ar[r]), "+v"(br[r]));
            float v8[8] = { ar[0], ar[1], ar[2], ar[3], br[0], br[1], br[2], br[3] };
            unsigned hbw[4], lbw[4];
            pack8(v8, hbw, lbw);
            bf16x8 Bh = __builtin_bit_cast(bf16x8, make_uint4(hbw[0], hbw[1], hbw[2], hbw[3]));
            bf16x8 Bl = __builtin_bit_cast(bf16x8, make_uint4(lbw[0], lbw[1], lbw[2], lbw[3]));
            const int t = 2 * m + half;
            bf16x8 A1h = frag_of(img1[(t * 2 + 0) * 64 + lane]);
            bf16x8 A1l = frag_of(img1[(t * 2 + 1) * 64 + lane]);
            dC = __builtin_amdgcn_mfma_f32_32x32x16_bf16(A1h, Bh, dC, 0, 0, 0);
            dC = __builtin_amdgcn_mfma_f32_32x32x16_bf16(A1h, Bl, dC, 0, 0, 0);
            dC = __builtin_amdgcn_mfma_f32_32x32x16_bf16(A1l, Bh, dC, 0, 0, 0);
        }
    }

    // redistribute centers: after swaps fid[r] = center of channel 4q+(r&3)+8(r>>2)
    #pragma unroll
    for (int j = 0; j < 4; ++j)
        asm("v_permlane32_swap_b32 %0, %1" : "+v"(fid[j]), "+v"(fid[j + 4]));

    const size_t pix = (size_t)h * WW + w;
    const float mk = mask[(size_t)b * HW + pix];
    float* __restrict__ xnb = xn + (size_t)b * CHW;
    #pragma unroll
    for (int r = 0; r < 8; ++r) {
        int c = 4 * q + (r & 3) + 8 * (r >> 2);
        xnb[c * HW + pix] = fid[r] + dC[r] * mk;
    }
}

// Per-step life kernel, 4 px/thread (the round-13 vectorized version, under
// bisect): post = maxpool3(xn[:,3]) > 0.1; out = xn * (pre & post).
__global__ __launch_bounds__(256) void ca_step_life(
    const float* __restrict__ xn,
    const float* __restrict__ pre,
    float* __restrict__ xout)
{
    const int tid = threadIdx.x;
    const int g = tid & 63;                  // 4-px group along w
    const int h = blockIdx.y * 4 + (tid >> 6);
    const int b = blockIdx.z;
    const int w4 = g * 4;
    const float* __restrict__ alpha = xn + ((size_t)b * CC + 3) * HW;

    const int hm1 = (h > 0) ? h - 1 : 0, hp1 = (h < HH - 1) ? h + 1 : h;
    const int ro[3] = { hm1 * WW, h * WW, hp1 * WW };
    const bool rok[3] = { h > 0, true, h < HH - 1 };

    float m0 = 0.f, m1 = 0.f, m2 = 0.f, m3 = 0.f;  // zero-pad semantics
    #pragma unroll
    for (int r = 0; r < 3; ++r) {
        f32x4 a = *reinterpret_cast<const f32x4*>(&alpha[ro[r] + w4]);  // 16B aligned
        float a0 = (w4 > 0)       ? alpha[ro[r] + w4 - 1] : 0.0f;
        float a5 = (w4 + 4 < WW)  ? alpha[ro[r] + w4 + 4] : 0.0f;
        float r0 = fmaxf(fmaxf(a0,  a.x), a.y);
        float r1 = fmaxf(fmaxf(a.x, a.y), a.z);
        float r2 = fmaxf(fmaxf(a.y, a.z), a.w);
        float r3 = fmaxf(fmaxf(a.z, a.w), a5);
        if (rok[r]) {   // wave-uniform
            m0 = fmaxf(m0, r0); m1 = fmaxf(m1, r1);
            m2 = fmaxf(m2, r2); m3 = fmaxf(m3, r3);
        }
    }

    const size_t pix = (size_t)h * WW + w4;
    f32x4 pr = *reinterpret_cast<const f32x4*>(&pre[(size_t)b * HW + pix]);
    f32x4 life;
    life.x = (m0 > 0.1f && pr.x > 0.5f) ? 1.0f : 0.0f;
    life.y = (m1 > 0.1f && pr.y > 0.5f) ? 1.0f : 0.0f;
    life.z = (m2 > 0.1f && pr.z > 0.5f) ? 1.0f : 0.0f;
    life.w = (m3 > 0.1f && pr.w > 0.5f) ? 1.0f : 0.0f;

    const float* __restrict__ xnb = xn + (size_t)b * CHW;
    float* __restrict__ xob = xout + (size_t)b * CHW;
    #pragma unroll
    for (int c = 0; c < 16; ++c) {
        f32x4 v = *reinterpret_cast<const f32x4*>(&xnb[c * HW + pix]);
        v.x *= life.x; v.y *= life.y; v.z *= life.z; v.w *= life.w;
        *reinterpret_cast<f32x4*>(&xob[c * HW + pix]) = v;
    }
}

extern "C" void kernel_launch(void* const* d_in, const int* in_sizes, int n_in,
                              void* d_out, int out_size, void* d_ws, size_t ws_size,
                              hipStream_t stream) {
    const float* x      = (const float*)d_in[0];  // [8,16,256,256]
    const float* fc0w   = (const float*)d_in[1];  // [128,48]
    const float* fc0b   = (const float*)d_in[2];  // [128]
    const float* fc1w   = (const float*)d_in[3];  // [16,128]
    const float* stoch  = (const float*)d_in[4];  // [4,8,1,256,256]
    float* out = (float*)d_out;

    float* ws    = (float*)d_ws;
    float* xn    = ws;                          // 8388608 floats
    float* xtmp  = ws + (size_t)BB * CHW;       // 8388608 floats
    float* pre   = xtmp + (size_t)BB * CHW;     // 524288 floats
    uint4* img0  = (uint4*)(pre + (size_t)BB * HW);   // 2048 uint4 (32 KB)
    uint4* img1  = img0 + 2048;                       // 1024 uint4 (16 KB)

    prep_frags<<<12, 256, 0, stream>>>(fc0w, fc0b, fc1w, img0, img1);

    dim3 gridM(WW / 64, HH / 4, BB);   // 512 threads = 8 waves = 64 px x 4 rows
    dim3 gridL(1, HH / 4, BB);         // 256 threads = 4 rows x 64 groups of 4 px

    for (int s = 0; s < 4; ++s) {
        const float* xin = (s == 0) ? x : xtmp;
        const float* msk = stoch + (size_t)s * BB * HW;
        ca_step_mlp<<<gridM, dim3(512), 0, stream>>>(xin, img0, img1, msk, xn, pre);
        float* xo = (s == 3) ? out : xtmp;
        ca_step_life<<<gridL, dim3(256), 0, stream>>>(xn, pre, xo);
    }
}